// Round 11
// baseline (204.367 us; speedup 1.0000x reference)
//
#include <hip/hip_runtime.h>

#define NPTS 4096
#define NBATCH 4
#define HDIM 192
#define CDIM 384

typedef _Float16 f16x8 __attribute__((ext_vector_type(8)));
typedef float f32x4 __attribute__((ext_vector_type(4)));

// ---------------- K0: W2 [192][384] f32 -> W2T [384][192] f16 ----------------
__global__ __launch_bounds__(256) void prep_w2(const float* __restrict__ W2,
                                               _Float16* __restrict__ W2T) {
  int i = blockIdx.x * 256 + threadIdx.x;
  if (i < HDIM * CDIM) {
    int h = i / CDIM, c = i % CDIM;
    W2T[c * HDIM + h] = (_Float16)W2[i];
  }
}

// ---------------- K1: KNN, filter-then-prune + per-query SHARED threshold ----------------
// (unchanged from R6..R10)
#define SCAP 30
#define FINF 3.4e38f

// macro, not lambda: a [&] lambda address-takes dl/il -> scratch spill (R2 lesson)
#define PRUNE()                                                                      \
  do {                                                                               \
    int mc = cnt;                                                                    \
    _Pragma("unroll")                                                                \
    for (int s = 32; s; s >>= 1) { int o = __shfl_xor(mc, s); mc = mc > o ? mc : o; }\
    mc = __builtin_amdgcn_readfirstlane(mc);                                         \
    for (int e = 0; e < mc; ++e) {                                                   \
      const int j = sstk[sbase + e] & 4095;                                          \
      const float dx = qx - spx[j];                                                  \
      const float dy = qy - spy[j];                                                  \
      const float dz = qz - spz[j];                                                  \
      const float d = __fadd_rn(__fadd_rn(__fmul_rn(dx, dx), __fmul_rn(dy, dy)),     \
                                __fmul_rn(dz, dz));                                  \
      const float v = (e < cnt && d < dl[15]) ? d : FINF;                            \
      bool cc[16];                                                                   \
      _Pragma("unroll")                                                              \
      for (int i = 0; i < 16; ++i) cc[i] = v < dl[i];                                \
      _Pragma("unroll")                                                              \
      for (int i = 15; i >= 1; --i) {                                                \
        dl[i] = cc[i] ? (cc[i - 1] ? dl[i - 1] : v) : dl[i];                         \
        il[i] = cc[i] ? (cc[i - 1] ? il[i - 1] : j) : il[i];                         \
      }                                                                              \
      dl[0] = cc[0] ? v : dl[0];                                                     \
      il[0] = cc[0] ? j : il[0];                                                     \
    }                                                                                \
    cnt = 0;                                                                         \
    thr = dl[15];                                                                    \
    atomicMin(&sThrU[ql], __float_as_uint(dl[15]));                                  \
  } while (0)

__global__ __launch_bounds__(512) void knn_kernel(const float* __restrict__ pts,
                                                  int* __restrict__ idx_out) {
  __shared__ float smem[12352];
  __shared__ float sstk_f[7680];
  __shared__ unsigned sThrU[32];
  unsigned short* sstk = (unsigned short*)sstk_f;

  float* spx = smem;
  float* spy = smem + 4096;
  float* spz = smem + 8192;

  const int t  = threadIdx.x;
  const int b  = blockIdx.x >> 7;
  const int qb = (blockIdx.x & 127) << 5;
  const float* P = pts + (size_t)b * NPTS * 3;

  for (int i = t; i < NPTS; i += 512) {
    spx[i] = P[3 * i + 0];
    spy[i] = P[3 * i + 1];
    spz[i] = P[3 * i + 2];
  }
  if (t < 32) sThrU[t] = __float_as_uint(FINF);
  __syncthreads();

  const int ql    = t & 31;
  const int q     = qb + ql;
  const int cid   = (t >> 5) & 15;
  const int cbase = cid << 8;
  const float qx = spx[q], qy = spy[q], qz = spz[q];

  float dl[16];
  int   il[16];
#pragma unroll
  for (int i = 0; i < 16; ++i) { dl[i] = FINF; il[i] = 0; }
  float thr = FINF;
  int   cnt = 0;
  const int sbase = t * SCAP;

  for (int jt = 0; jt < 256; jt += 8) {
    {  // refresh admission threshold (volatile: must observe other waves' atomicMin)
      const unsigned tb = ((volatile unsigned*)sThrU)[ql];
      thr = fminf(dl[15], __uint_as_float(tb));
    }
    const int jb = cbase + jt;
    const f32x4 x0 = *(const f32x4*)(spx + jb);
    const f32x4 x1 = *(const f32x4*)(spx + jb + 4);
    const f32x4 y0 = *(const f32x4*)(spy + jb);
    const f32x4 y1 = *(const f32x4*)(spy + jb + 4);
    const f32x4 z0 = *(const f32x4*)(spz + jb);
    const f32x4 z1 = *(const f32x4*)(spz + jb + 4);
#pragma unroll
    for (int u = 0; u < 8; ++u) {
      const float px = (u < 4) ? x0[u & 3] : x1[u & 3];
      const float py = (u < 4) ? y0[u & 3] : y1[u & 3];
      const float pz = (u < 4) ? z0[u & 3] : z1[u & 3];
      const float dx = qx - px;
      const float dy = qy - py;
      const float dz = qz - pz;
      // EXACT match to numpy/jax: ((dx*dx + dy*dy) + dz*dz), f32, no FMA contraction
      const float d = __fadd_rn(__fadd_rn(__fmul_rn(dx, dx), __fmul_rn(dy, dy)),
                                __fmul_rn(dz, dz));
      if (d <= thr) { sstk[sbase + cnt] = (unsigned short)(jb + u); ++cnt; }
    }
    if (__any(cnt >= SCAP - 8)) PRUNE();
  }
  PRUNE();

  __syncthreads();

  float*          md = smem;
  unsigned short* mi = (unsigned short*)(smem + 8224);
  const int lbase = ql * 257 + cid * 16;
#pragma unroll
  for (int i = 0; i < 16; ++i) {
    md[lbase + i] = dl[i];
    mi[lbase + i] = (unsigned short)il[i];
  }
  __syncthreads();

  float*          od = sstk_f;
  unsigned short* oi = (unsigned short*)(sstk_f + 2080);
  if (t < 128) {
    const int mq = t >> 2, g = t & 3;
    const int base = mq * 257 + g * 64;
    int p0 = 0, p1 = 0, p2 = 0, p3 = 0;
    const int ob = mq * 65 + g * 16;
    for (int r = 0; r < 16; ++r) {
      const float d0 = md[base + p0];
      const float d1 = md[base + 16 + p1];
      const float d2 = md[base + 32 + p2];
      const float d3 = md[base + 48 + p3];
      int bw = 0; float bd = d0;
      if (d1 < bd) { bd = d1; bw = 1; }
      if (d2 < bd) { bd = d2; bw = 2; }
      if (d3 < bd) { bd = d3; bw = 3; }
      const unsigned short bi = (bw == 0) ? mi[base + p0]
                              : (bw == 1) ? mi[base + 16 + p1]
                              : (bw == 2) ? mi[base + 32 + p2]
                                          : mi[base + 48 + p3];
      od[ob + r] = bd;
      oi[ob + r] = bi;
      p0 += (bw == 0); p1 += (bw == 1); p2 += (bw == 2); p3 += (bw == 3);
    }
  }
  __syncthreads();

  if (t < 32) {
    const int base = t * 65;
    int p0 = 0, p1 = 0, p2 = 0, p3 = 0;
    int* op = idx_out + (((size_t)b * NPTS + qb + t) << 4);
    for (int r = 0; r < 16; ++r) {
      const float d0 = od[base + p0];
      const float d1 = od[base + 16 + p1];
      const float d2 = od[base + 32 + p2];
      const float d3 = od[base + 48 + p3];
      int bw = 0; float bd = d0;
      if (d1 < bd) { bd = d1; bw = 1; }
      if (d2 < bd) { bd = d2; bw = 2; }
      if (d3 < bd) { bd = d3; bw = 3; }
      const unsigned short bi = (bw == 0) ? oi[base + p0]
                              : (bw == 1) ? oi[base + 16 + p1]
                              : (bw == 2) ? oi[base + 32 + p2]
                                          : oi[base + 48 + p3];
      op[r] = (int)bi;
      p0 += (bw == 0); p1 += (bw == 1); p2 += (bw == 2); p3 += (bw == 3);
    }
  }
}

// ---------------- K2: fused MLP, 4 indep waves/block, 4 q/wave, B-prefetch pipeline --
// R10: four structures all hit ~110us = latency exposure (17% issue-slot util, 1-wave
// workgroups, serial load->MFMA->shfl per ct). Fix: (a) 256-thr blocks of 4 independent
// waves (no barriers/LDS) for denser residency; (b) software-pipelined B: prefetch
// ct+1's 6 frags + b2 before ct's MFMAs so ~200cy L2 latency hides under compute.
__global__ __launch_bounds__(256, 2) void mlp_kernel(const float* __restrict__ pts,
                                                     const int* __restrict__ idx,
                                                     const float* __restrict__ W1,
                                                     const float* __restrict__ b1,
                                                     const _Float16* __restrict__ W2T,
                                                     const float* __restrict__ b2,
                                                     float* __restrict__ out) {
  const int bid = blockIdx.x;          // 1024 = 4 batches * 256 blocks
  const int b   = bid >> 8;
  const int t   = threadIdx.x;
  const int wv  = t >> 6;              // 4 independent waves
  const int q0  = ((bid & 255) << 4) + (wv << 2);   // 4 queries per wave
  const float* P = pts + (size_t)b * NPTS * 3;
  const int l   = t & 63;
  const int r   = l & 15;              // neighbor slot (A-frag row)
  const int kg  = l >> 4;              // k-slice 0..3 (A-frag k-group)

  // ---- gathers: 4 queries, neighbor slot r each ----
  float f[4][6];
#pragma unroll
  for (int qi = 0; qi < 4; ++qi) {
    const int qq = q0 + qi;
    const int nb = idx[(((size_t)b * NPTS + qq) << 4) + r];
    const float ax = P[qq * 3 + 0], ay = P[qq * 3 + 1], az = P[qq * 3 + 2];
    f[qi][0] = P[nb * 3 + 0] - ax;
    f[qi][1] = P[nb * 3 + 1] - ay;
    f[qi][2] = P[nb * 3 + 2] - az;
    f[qi][3] = ax; f[qi][4] = ay; f[qi][5] = az;
  }

  // ---- stage layer1 -> A-fragments in registers ----
  // lane l computes h[kt*32 + kg*8 .. +8] for neighbor row r == exactly the
  // mfma_f32_16x16x32_f16 A-frag mapping (lane = kgr*16 + ln15).
  f16x8 af[4][6];
#pragma unroll
  for (int kt = 0; kt < 6; ++kt) {
    const int h0 = kt * 32 + kg * 8;
    const f32x4 bb0 = *(const f32x4*)(b1 + h0);
    const f32x4 bb1 = *(const f32x4*)(b1 + h0 + 4);
    f32x4 w0[6], w1[6];
#pragma unroll
    for (int in = 0; in < 6; ++in) {
      w0[in] = *(const f32x4*)(W1 + in * HDIM + h0);
      w1[in] = *(const f32x4*)(W1 + in * HDIM + h0 + 4);
    }
#pragma unroll
    for (int qi = 0; qi < 4; ++qi) {
      f32x4 a0 = bb0, a1 = bb1;
#pragma unroll
      for (int in = 0; in < 6; ++in) {
        a0 += f[qi][in] * w0[in];
        a1 += f[qi][in] * w1[in];
      }
      f16x8 v;
#pragma unroll
      for (int j = 0; j < 4; ++j) {   // same swish expression as R4..R10 (absmax-stable)
        v[j]     = (_Float16)(a0[j] * __builtin_amdgcn_rcpf(1.0f + __expf(-a0[j])));
        v[j + 4] = (_Float16)(a1[j] * __builtin_amdgcn_rcpf(1.0f + __expf(-a1[j])));
      }
      af[qi][kt] = v;
    }
  }

  // ---- MFMA + maxpool over 24 channel tiles, software-pipelined B ----
  const int kofs = kg * 8;
  const size_t orow = (size_t)b * NPTS + q0;

  f16x8 bcur[6];
  float bbc;
  {
    const _Float16* bp = W2T + (size_t)r * HDIM + kofs;   // ct=0 -> c=r
#pragma unroll
    for (int kt = 0; kt < 6; ++kt) bcur[kt] = *(const f16x8*)(bp + kt * 32);
    bbc = b2[r];
  }

  for (int ct = 0; ct < 24; ++ct) {
    const int c = ct * 16 + r;
    // prefetch next tile's B + b2 (independent of this tile's MFMAs)
    f16x8 bnxt[6];
    float bbn;
    {
      const int cn = (ct < 23 ? ct + 1 : 23) * 16 + r;
      const _Float16* bp = W2T + (size_t)cn * HDIM + kofs;
#pragma unroll
      for (int kt = 0; kt < 6; ++kt) bnxt[kt] = *(const f16x8*)(bp + kt * 32);
      bbn = b2[cn];
    }

    f32x4 acc[4];
#pragma unroll
    for (int qi = 0; qi < 4; ++qi) acc[qi] = f32x4{0.f, 0.f, 0.f, 0.f};
#pragma unroll
    for (int kt = 0; kt < 6; ++kt)
#pragma unroll
      for (int qi = 0; qi < 4; ++qi)
        acc[qi] = __builtin_amdgcn_mfma_f32_16x16x32_f16(af[qi][kt], bcur[kt], acc[qi], 0, 0, 0);

    // C/D: col=lane&15 (=channel), row=(lane>>4)*4+reg (=neighbor) -> max over rows
#pragma unroll
    for (int qi = 0; qi < 4; ++qi) {
      float m = fmaxf(fmaxf(acc[qi][0], acc[qi][1]), fmaxf(acc[qi][2], acc[qi][3]));
      m = fmaxf(m, __shfl_xor(m, 16));
      m = fmaxf(m, __shfl_xor(m, 32));
      if (l < 16)
        out[(orow + qi) * CDIM + c] = m + bbc;
    }

#pragma unroll
    for (int kt = 0; kt < 6; ++kt) bcur[kt] = bnxt[kt];
    bbc = bbn;
  }
}

extern "C" void kernel_launch(void* const* d_in, const int* in_sizes, int n_in,
                              void* d_out, int out_size, void* d_ws, size_t ws_size,
                              hipStream_t stream) {
  const float* point = (const float*)d_in[0];
  const float* W1    = (const float*)d_in[1];
  const float* b1    = (const float*)d_in[2];
  const float* W2    = (const float*)d_in[3];
  const float* b2    = (const float*)d_in[4];

  int*      idx_ws = (int*)d_ws;
  _Float16* W2T    = (_Float16*)((char*)d_ws + (1 << 20));

  prep_w2<<<(HDIM * CDIM + 255) / 256, 256, 0, stream>>>(W2, W2T);
  knn_kernel<<<512, 512, 0, stream>>>(point, idx_ws);
  mlp_kernel<<<NBATCH * 256, 256, 0, stream>>>(point, idx_ws, W1, b1, W2T, b2, (float*)d_out);
}

// Round 12
// 149.031 us; speedup vs baseline: 1.3713x; 1.3713x over previous
//
#include <hip/hip_runtime.h>

#define NPTS 4096
#define NBATCH 4
#define HDIM 192
#define CDIM 384

typedef _Float16 f16x8 __attribute__((ext_vector_type(8)));
typedef float f32x4 __attribute__((ext_vector_type(4)));

// ---------------- K0: W2 [192][384] f32 -> fragment-major f16 chunks ----------------
// chunk j (16B, 8 f16) = B-frag for (ct=j/384, kt=(j>>6)%6, lane=j&63 -> r=lane&15,
// kg=lane>>4): W2[h0+e][c], c=ct*16+r, h0=kt*32+kg*8. mlp copies this linearly to LDS
// and reads at ((ct*6+kt)*64+lane)*16B -> lane-linear, conflict-free both sides.
__global__ __launch_bounds__(256) void prep_w2(const float* __restrict__ W2,
                                               _Float16* __restrict__ W2F) {
  const int j = blockIdx.x * 256 + threadIdx.x;   // 9216 chunks
  if (j < 9216) {
    const int lane = j & 63, r = lane & 15, kg = lane >> 4;
    const int kt = (j >> 6) % 6, ct = j / 384;
    const int c = ct * 16 + r, h0 = kt * 32 + kg * 8;
    f16x8 v;
#pragma unroll
    for (int e = 0; e < 8; ++e) v[e] = (_Float16)W2[(size_t)(h0 + e) * CDIM + c];
    *(f16x8*)(W2F + (size_t)j * 8) = v;
  }
}

// ---------------- K1: KNN, filter-then-prune + per-query SHARED threshold ----------------
// (unchanged from R6..R11)
#define SCAP 30
#define FINF 3.4e38f

// macro, not lambda: a [&] lambda address-takes dl/il -> scratch spill (R2 lesson)
#define PRUNE()                                                                      \
  do {                                                                               \
    int mc = cnt;                                                                    \
    _Pragma("unroll")                                                                \
    for (int s = 32; s; s >>= 1) { int o = __shfl_xor(mc, s); mc = mc > o ? mc : o; }\
    mc = __builtin_amdgcn_readfirstlane(mc);                                         \
    for (int e = 0; e < mc; ++e) {                                                   \
      const int j = sstk[sbase + e] & 4095;                                          \
      const float dx = qx - spx[j];                                                  \
      const float dy = qy - spy[j];                                                  \
      const float dz = qz - spz[j];                                                  \
      const float d = __fadd_rn(__fadd_rn(__fmul_rn(dx, dx), __fmul_rn(dy, dy)),     \
                                __fmul_rn(dz, dz));                                  \
      const float v = (e < cnt && d < dl[15]) ? d : FINF;                            \
      bool cc[16];                                                                   \
      _Pragma("unroll")                                                              \
      for (int i = 0; i < 16; ++i) cc[i] = v < dl[i];                                \
      _Pragma("unroll")                                                              \
      for (int i = 15; i >= 1; --i) {                                                \
        dl[i] = cc[i] ? (cc[i - 1] ? dl[i - 1] : v) : dl[i];                         \
        il[i] = cc[i] ? (cc[i - 1] ? il[i - 1] : j) : il[i];                         \
      }                                                                              \
      dl[0] = cc[0] ? v : dl[0];                                                     \
      il[0] = cc[0] ? j : il[0];                                                     \
    }                                                                                \
    cnt = 0;                                                                         \
    thr = dl[15];                                                                    \
    atomicMin(&sThrU[ql], __float_as_uint(dl[15]));                                  \
  } while (0)

__global__ __launch_bounds__(512) void knn_kernel(const float* __restrict__ pts,
                                                  int* __restrict__ idx_out) {
  __shared__ float smem[12352];
  __shared__ float sstk_f[7680];
  __shared__ unsigned sThrU[32];
  unsigned short* sstk = (unsigned short*)sstk_f;

  float* spx = smem;
  float* spy = smem + 4096;
  float* spz = smem + 8192;

  const int t  = threadIdx.x;
  const int b  = blockIdx.x >> 7;
  const int qb = (blockIdx.x & 127) << 5;
  const float* P = pts + (size_t)b * NPTS * 3;

  for (int i = t; i < NPTS; i += 512) {
    spx[i] = P[3 * i + 0];
    spy[i] = P[3 * i + 1];
    spz[i] = P[3 * i + 2];
  }
  if (t < 32) sThrU[t] = __float_as_uint(FINF);
  __syncthreads();

  const int ql    = t & 31;
  const int q     = qb + ql;
  const int cid   = (t >> 5) & 15;
  const int cbase = cid << 8;
  const float qx = spx[q], qy = spy[q], qz = spz[q];

  float dl[16];
  int   il[16];
#pragma unroll
  for (int i = 0; i < 16; ++i) { dl[i] = FINF; il[i] = 0; }
  float thr = FINF;
  int   cnt = 0;
  const int sbase = t * SCAP;

  for (int jt = 0; jt < 256; jt += 8) {
    {  // refresh admission threshold (volatile: must observe other waves' atomicMin)
      const unsigned tb = ((volatile unsigned*)sThrU)[ql];
      thr = fminf(dl[15], __uint_as_float(tb));
    }
    const int jb = cbase + jt;
    const f32x4 x0 = *(const f32x4*)(spx + jb);
    const f32x4 x1 = *(const f32x4*)(spx + jb + 4);
    const f32x4 y0 = *(const f32x4*)(spy + jb);
    const f32x4 y1 = *(const f32x4*)(spy + jb + 4);
    const f32x4 z0 = *(const f32x4*)(spz + jb);
    const f32x4 z1 = *(const f32x4*)(spz + jb + 4);
#pragma unroll
    for (int u = 0; u < 8; ++u) {
      const float px = (u < 4) ? x0[u & 3] : x1[u & 3];
      const float py = (u < 4) ? y0[u & 3] : y1[u & 3];
      const float pz = (u < 4) ? z0[u & 3] : z1[u & 3];
      const float dx = qx - px;
      const float dy = qy - py;
      const float dz = qz - pz;
      // EXACT match to numpy/jax: ((dx*dx + dy*dy) + dz*dz), f32, no FMA contraction
      const float d = __fadd_rn(__fadd_rn(__fmul_rn(dx, dx), __fmul_rn(dy, dy)),
                                __fmul_rn(dz, dz));
      if (d <= thr) { sstk[sbase + cnt] = (unsigned short)(jb + u); ++cnt; }
    }
    if (__any(cnt >= SCAP - 8)) PRUNE();
  }
  PRUNE();

  __syncthreads();

  float*          md = smem;
  unsigned short* mi = (unsigned short*)(smem + 8224);
  const int lbase = ql * 257 + cid * 16;
#pragma unroll
  for (int i = 0; i < 16; ++i) {
    md[lbase + i] = dl[i];
    mi[lbase + i] = (unsigned short)il[i];
  }
  __syncthreads();

  float*          od = sstk_f;
  unsigned short* oi = (unsigned short*)(sstk_f + 2080);
  if (t < 128) {
    const int mq = t >> 2, g = t & 3;
    const int base = mq * 257 + g * 64;
    int p0 = 0, p1 = 0, p2 = 0, p3 = 0;
    const int ob = mq * 65 + g * 16;
    for (int r = 0; r < 16; ++r) {
      const float d0 = md[base + p0];
      const float d1 = md[base + 16 + p1];
      const float d2 = md[base + 32 + p2];
      const float d3 = md[base + 48 + p3];
      int bw = 0; float bd = d0;
      if (d1 < bd) { bd = d1; bw = 1; }
      if (d2 < bd) { bd = d2; bw = 2; }
      if (d3 < bd) { bd = d3; bw = 3; }
      const unsigned short bi = (bw == 0) ? mi[base + p0]
                              : (bw == 1) ? mi[base + 16 + p1]
                              : (bw == 2) ? mi[base + 32 + p2]
                                          : mi[base + 48 + p3];
      od[ob + r] = bd;
      oi[ob + r] = bi;
      p0 += (bw == 0); p1 += (bw == 1); p2 += (bw == 2); p3 += (bw == 3);
    }
  }
  __syncthreads();

  if (t < 32) {
    const int base = t * 65;
    int p0 = 0, p1 = 0, p2 = 0, p3 = 0;
    int* op = idx_out + (((size_t)b * NPTS + qb + t) << 4);
    for (int r = 0; r < 16; ++r) {
      const float d0 = od[base + p0];
      const float d1 = od[base + 16 + p1];
      const float d2 = od[base + 32 + p2];
      const float d3 = od[base + 48 + p3];
      int bw = 0; float bd = d0;
      if (d1 < bd) { bd = d1; bw = 1; }
      if (d2 < bd) { bd = d2; bw = 2; }
      if (d3 < bd) { bd = d3; bw = 3; }
      const unsigned short bi = (bw == 0) ? oi[base + p0]
                              : (bw == 1) ? oi[base + 16 + p1]
                              : (bw == 2) ? oi[base + 32 + p2]
                                          : oi[base + 48 + p3];
      op[r] = (int)bi;
      p0 += (bw == 0); p1 += (bw == 1); p2 += (bw == 2); p3 += (bw == 3);
    }
  }
}

// ---------------- K2: fused MLP, ALL of W2 in LDS (144 KiB), A in registers ----------
// R4-R11 wall (~110us): per-ct global B loads (~200cy L2) with ~2 eff. waves/SIMD; more
// regs to hide it -> spill (R9/R11). Fix the mechanism: W2 fragment-major in LDS, read
// via lane-linear ds_read_b128 (R5-verified 0-conflict pattern); ZERO global loads in
// the MFMA phase. 512 thr = 8 waves x 4q (R10's proven af[4][6] staging, identical
// numerics); 512 blocks (2 passes/CU); one barrier; no min-waves bound (R9/R11 lesson).
__global__ __launch_bounds__(512) void mlp_kernel(const float* __restrict__ pts,
                                                  const int* __restrict__ idx,
                                                  const float* __restrict__ W1,
                                                  const float* __restrict__ b1,
                                                  const _Float16* __restrict__ W2F,
                                                  const float* __restrict__ b2,
                                                  float* __restrict__ out) {
  __shared__ _Float16 sB[73728];       // 144 KiB: all of W2, fragment-major

  const int bid = blockIdx.x;          // 512 = 4 batches * 128 blocks
  const int b   = bid >> 7;
  const int t   = threadIdx.x;
  const int wv  = t >> 6;              // 8 waves
  const int q0  = ((bid & 127) << 5) + (wv << 2);   // 4 queries per wave
  const float* P = pts + (size_t)b * NPTS * 3;
  const int l   = t & 63;
  const int r   = l & 15;              // neighbor slot (A-frag row)
  const int kg  = l >> 4;              // k-slice 0..3 (A-frag k-group)

  // ---- fill LDS with W2 fragments (lane-linear, conflict-free) ----
#pragma unroll
  for (int i = 0; i < 18; ++i) {
    const int j = i * 512 + t;         // 9216 chunks
    *(f16x8*)(sB + (size_t)j * 8) = *(const f16x8*)(W2F + (size_t)j * 8);
  }

  // ---- gathers: 4 queries, neighbor slot r each ----
  float f[4][6];
#pragma unroll
  for (int qi = 0; qi < 4; ++qi) {
    const int qq = q0 + qi;
    const int nb = idx[(((size_t)b * NPTS + qq) << 4) + r];
    const float ax = P[qq * 3 + 0], ay = P[qq * 3 + 1], az = P[qq * 3 + 2];
    f[qi][0] = P[nb * 3 + 0] - ax;
    f[qi][1] = P[nb * 3 + 1] - ay;
    f[qi][2] = P[nb * 3 + 2] - az;
    f[qi][3] = ax; f[qi][4] = ay; f[qi][5] = az;
  }

  // ---- stage layer1 -> A-fragments in registers (identical numerics to R10) ----
  f16x8 af[4][6];
#pragma unroll
  for (int kt = 0; kt < 6; ++kt) {
    const int h0 = kt * 32 + kg * 8;
    const f32x4 bb0 = *(const f32x4*)(b1 + h0);
    const f32x4 bb1 = *(const f32x4*)(b1 + h0 + 4);
    f32x4 w0[6], w1[6];
#pragma unroll
    for (int in = 0; in < 6; ++in) {
      w0[in] = *(const f32x4*)(W1 + in * HDIM + h0);
      w1[in] = *(const f32x4*)(W1 + in * HDIM + h0 + 4);
    }
#pragma unroll
    for (int qi = 0; qi < 4; ++qi) {
      f32x4 a0 = bb0, a1 = bb1;
#pragma unroll
      for (int in = 0; in < 6; ++in) {
        a0 += f[qi][in] * w0[in];
        a1 += f[qi][in] * w1[in];
      }
      f16x8 v;
#pragma unroll
      for (int j = 0; j < 4; ++j) {   // same swish expression as R4..R11 (absmax-stable)
        v[j]     = (_Float16)(a0[j] * __builtin_amdgcn_rcpf(1.0f + __expf(-a0[j])));
        v[j + 4] = (_Float16)(a1[j] * __builtin_amdgcn_rcpf(1.0f + __expf(-a1[j])));
      }
      af[qi][kt] = v;
    }
  }
  __syncthreads();   // LDS fill complete (fill loads + staging overlap above)

  // ---- MFMA + maxpool over 24 channel tiles; B from LDS ----
  const size_t orow = (size_t)b * NPTS + q0;
  const _Float16* bp = sB + (size_t)l * 8;   // chunk position == lane

  for (int ct = 0; ct < 24; ++ct) {
    const int c = ct * 16 + r;
    f16x8 bfr[6];
#pragma unroll
    for (int kt = 0; kt < 6; ++kt)
      bfr[kt] = *(const f16x8*)(bp + (size_t)(ct * 6 + kt) * 512);  // +64 chunks each

    f32x4 acc[4];
#pragma unroll
    for (int qi = 0; qi < 4; ++qi) acc[qi] = f32x4{0.f, 0.f, 0.f, 0.f};
#pragma unroll
    for (int kt = 0; kt < 6; ++kt)
#pragma unroll
      for (int qi = 0; qi < 4; ++qi)
        acc[qi] = __builtin_amdgcn_mfma_f32_16x16x32_f16(af[qi][kt], bfr[kt], acc[qi], 0, 0, 0);

    const float bb = b2[c];
    // C/D: col=lane&15 (=channel), row=(lane>>4)*4+reg (=neighbor) -> max over rows
#pragma unroll
    for (int qi = 0; qi < 4; ++qi) {
      float m = fmaxf(fmaxf(acc[qi][0], acc[qi][1]), fmaxf(acc[qi][2], acc[qi][3]));
      m = fmaxf(m, __shfl_xor(m, 16));
      m = fmaxf(m, __shfl_xor(m, 32));
      if (l < 16)
        out[(orow + qi) * CDIM + c] = m + bb;
    }
  }
}

extern "C" void kernel_launch(void* const* d_in, const int* in_sizes, int n_in,
                              void* d_out, int out_size, void* d_ws, size_t ws_size,
                              hipStream_t stream) {
  const float* point = (const float*)d_in[0];
  const float* W1    = (const float*)d_in[1];
  const float* b1    = (const float*)d_in[2];
  const float* W2    = (const float*)d_in[3];
  const float* b2    = (const float*)d_in[4];

  int*      idx_ws = (int*)d_ws;
  _Float16* W2F    = (_Float16*)((char*)d_ws + (1 << 20));

  prep_w2<<<36, 256, 0, stream>>>(W2, W2F);
  knn_kernel<<<512, 512, 0, stream>>>(point, idx_ws);
  mlp_kernel<<<512, 512, 0, stream>>>(point, idx_ws, W1, b1, W2F, b2, (float*)d_out);
}